// Round 4
// baseline (192.127 us; speedup 1.0000x reference)
//
#include <hip/hip_runtime.h>
#include <hip/hip_bf16.h>

#define DIM 256
#define MEMN 512
#define TEMPF 10.0f

typedef float f32x4 __attribute__((ext_vector_type(4)));
typedef __bf16 bf16x8 __attribute__((ext_vector_type(8)));
typedef unsigned int u32;
typedef unsigned short u16;
typedef u32 u32x4 __attribute__((ext_vector_type(4)));

typedef __attribute__((address_space(1))) unsigned int as1_u32;
typedef __attribute__((address_space(3))) unsigned int as3_u32;

__device__ __forceinline__ void gll16(const void* gp, void* lp) {
  __builtin_amdgcn_global_load_lds((const as1_u32*)gp, (as3_u32*)lp, 16, 0, 0);
}

__device__ __forceinline__ u16 bf16bits(float x) {
  __bf16 h = (__bf16)x;
  return __builtin_bit_cast(u16, h);
}
__device__ __forceinline__ u32 pack2(float a, float b) {
  return (u32)bf16bits(a) | ((u32)bf16bits(b) << 16);
}

// KnFrag[kc][mt][lane][j] = Kn_norm[mt*16+(lane&15)][kc*32+(lane>>4)*8+j], kc<8, mt<32
__global__ void prep_keys(const float* __restrict__ keys, u16* __restrict__ knf) {
  int lane = threadIdx.x & 63;
  int m = blockIdx.x * 4 + (threadIdx.x >> 6);
  float4 v = *reinterpret_cast<const float4*>(keys + (size_t)m * DIM + lane * 4);
  float ss = v.x*v.x + v.y*v.y + v.z*v.z + v.w*v.w;
  #pragma unroll
  for (int o = 1; o < 64; o <<= 1) ss += __shfl_xor(ss, o);
  float rn = 1.0f / fmaxf(sqrtf(ss), 1e-12f);
  float vals[4] = {v.x*rn, v.y*rn, v.z*rn, v.w*rn};
  int mt = m >> 4, ml = m & 15;
  #pragma unroll
  for (int t = 0; t < 4; ++t) {
    int d = lane * 4 + t;
    int kc = d >> 5, gg = (d >> 3) & 3, j = d & 7;
    knf[(size_t)((kc*32 + mt)*64 + gg*16 + ml)*8 + j] = bf16bits(vals[t]);
  }
}

// VtFrag[kc][dt][lane][j] = V[kc*32+(lane>>4)*8+j][dt*16+(lane&15)], kc<16, dt<16
__global__ void prep_vals(const float* __restrict__ mv, u16* __restrict__ vtf) {
  int lane = threadIdx.x & 63;
  int m = blockIdx.x * 4 + (threadIdx.x >> 6);
  float4 v = *reinterpret_cast<const float4*>(mv + (size_t)m * DIM + lane * 4);
  float vals[4] = {v.x, v.y, v.z, v.w};
  int kc = m >> 5, gg = (m >> 3) & 3, j = m & 7;
  #pragma unroll
  for (int t = 0; t < 4; ++t) {
    int d = lane * 4 + t;
    int dt = d >> 4, dl = d & 15;
    vtf[(size_t)((kc*16 + dt)*64 + gg*16 + dl)*8 + j] = bf16bits(vals[t]);
  }
}

// Counted vmcnt + FULL lgkmcnt drain before each barrier.
// lgkmcnt(0) is the WAR fix: it empties this wave's DS-read queue before the
// barrier, so no wave can still have in-flight ds_reads of a buffer another
// wave is about to overwrite via global_load_lds (rule #18: the consuming
// MFMAs — and their compiler lgkm waits — may sink past a raw s_barrier).
#define WAITCNTS(N) asm volatile("s_waitcnt vmcnt(" #N ") lgkmcnt(0)" ::: "memory")
// order pin: no codegen, but memory ops cannot cross
#define CLOBBER  asm volatile("" ::: "memory")
// full scheduler fence: nothing crosses
#define SCHEDB   __builtin_amdgcn_sched_barrier(0)

// Main fused kernel. 256 threads (4 waves), 64 rows/block.
// 16KB phases, 4-buffer LDS rotation, depth-3 prefetch, per phase:
// { s_waitcnt vmcnt(N) lgkmcnt(0); s_barrier; sched_barrier; stage; MFMAs }.
__global__ __launch_bounds__(256, 2) void fused_main(
    const float* __restrict__ q, const u16* __restrict__ knf,
    const u16* __restrict__ vtf, float* __restrict__ out_o,
    float* __restrict__ out_w, float* __restrict__ out_s) {
  __shared__ __align__(16) char lds[65536];   // 4 x 16KB rotating buffers
  const int tid = threadIdx.x;
  const int wave = tid >> 6, lane = tid & 63;
  const int g = lane >> 4, c = lane & 15;
  const int row = blockIdx.x * 64 + wave * 16 + c;

  const char* kptr = (const char*)knf;
  const char* vptr = (const char*)vtf;

  // 16KB cooperative stage: 4 gll16/thread, linear copy, wave-uniform LDS base
  auto stage16 = [&](const char* src, char* dst) {
    #pragma unroll
    for (int i = 0; i < 4; ++i)
      gll16(src + i*4096 + tid*16, dst + i*4096 + wave*1024);
  };

  // ---- Q loads FIRST (oldest in the vmcnt stream), then pinned K0,K1,K2
  float qv[64];
  const float* qrow = q + (size_t)row * DIM + g * 8;
  #pragma unroll
  for (int kc = 0; kc < 8; ++kc) {
    float4 a = *reinterpret_cast<const float4*>(qrow + kc * 32);
    float4 b = *reinterpret_cast<const float4*>(qrow + kc * 32 + 4);
    qv[kc*8+0]=a.x; qv[kc*8+1]=a.y; qv[kc*8+2]=a.z; qv[kc*8+3]=a.w;
    qv[kc*8+4]=b.x; qv[kc*8+5]=b.y; qv[kc*8+6]=b.z; qv[kc*8+7]=b.w;
  }
  CLOBBER;
  stage16(kptr + 0*16384, lds + 0*16384); CLOBBER;
  stage16(kptr + 1*16384, lds + 1*16384); CLOBBER;
  stage16(kptr + 2*16384, lds + 2*16384); CLOBBER;

  // scene diff + L2 norm + bf16 fragments (hides stage latency)
  float sd = 0.f, ss = 0.f;
  #pragma unroll
  for (int k = 0; k < 64; ++k) {
    float nb = __shfl_down(qv[k], 1);
    float d0 = nb - qv[k];
    sd += d0 * d0;
    ss += qv[k] * qv[k];
  }
  sd += __shfl_xor(sd, 16); sd += __shfl_xor(sd, 32);
  ss += __shfl_xor(ss, 16); ss += __shfl_xor(ss, 32);
  if (g == 0 && c < 15)
    out_s[row] = (sqrtf(sd) < 0.8f) ? 1.0f : 0.0f;
  float rn = 1.0f / fmaxf(sqrtf(ss), 1e-12f);
  bf16x8 qbf[8];
  #pragma unroll
  for (int kc = 0; kc < 8; ++kc) {
    #pragma unroll
    for (int j = 0; j < 8; ++j) qbf[kc][j] = (__bf16)(qv[kc*8+j] * rn);
  }

  f32x4 acc[32];
  #pragma unroll
  for (int mt = 0; mt < 32; ++mt) { f32x4 z = {}; acc[mt] = z; }

  // GEMM1 phase P: kc=P>>1, m-half=(P&1); 16 MFMA on buf P&3
#define G1C(P) { \
    const char* bufp = lds + ((P)&3)*16384; \
    _Pragma("unroll") \
    for (int mt = 0; mt < 16; ++mt) { \
      bf16x8 af = *reinterpret_cast<const bf16x8*>(bufp + mt*1024 + lane*16); \
      acc[((P)&1)*16+mt] = __builtin_amdgcn_mfma_f32_16x16x32_bf16(af, qbf[(P)>>1], acc[((P)&1)*16+mt], 0, 0, 0); \
    } }

#define PH(NV, SRC, DB) WAITCNTS(NV); __builtin_amdgcn_s_barrier(); SCHEDB; stage16((SRC), lds + (DB)*16384);
#define PHX(NV) WAITCNTS(NV); __builtin_amdgcn_s_barrier(); SCHEDB;

  // ---- GEMM1: 16 phases; stage K(p+3) (p<=12), then V0..V2 (p=13..15)
  // vmcnt(8): the 8 newest ops are the two later stages -> stage p complete.
  PH(8, kptr+ 3*16384, 3)  G1C(0)
  PH(8, kptr+ 4*16384, 0)  G1C(1)
  PH(8, kptr+ 5*16384, 1)  G1C(2)
  PH(8, kptr+ 6*16384, 2)  G1C(3)
  PH(8, kptr+ 7*16384, 3)  G1C(4)
  PH(8, kptr+ 8*16384, 0)  G1C(5)
  PH(8, kptr+ 9*16384, 1)  G1C(6)
  PH(8, kptr+10*16384, 2)  G1C(7)
  PH(8, kptr+11*16384, 3)  G1C(8)
  PH(8, kptr+12*16384, 0)  G1C(9)
  PH(8, kptr+13*16384, 1)  G1C(10)
  PH(8, kptr+14*16384, 2)  G1C(11)
  PH(8, kptr+15*16384, 3)  G1C(12)
  PH(8, vptr+ 0*16384, 0)  G1C(13)
  PH(8, vptr+ 1*16384, 1)  G1C(14)
  PH(8, vptr+ 2*16384, 2)  G1C(15)

  // ---- softmax (|logit|<=10: no max-sub needed); V0..V2 staging in flight
  float sum = 0.f;
  #pragma unroll
  for (int mt = 0; mt < 32; ++mt) {
    #pragma unroll
    for (int i = 0; i < 4; ++i) {
      float e = __expf(acc[mt][i] * TEMPF);
      acc[mt][i] = e;
      sum += e;
    }
  }
  sum += __shfl_xor(sum, 16); sum += __shfl_xor(sum, 32);
  float rcp = 1.0f / sum;

  // pin: all V2 stage ops are issued BEFORE any W store (count integrity)
  CLOBBER;

  // W store burst (32 float4) + bf16 pack for GEMM2 B-frags
  u32 hpair[64];
  float* wrow = out_w + (size_t)row * MEMN + g * 4;
  #pragma unroll
  for (int mt = 0; mt < 32; ++mt) {
    float4 wv = { acc[mt][0]*rcp, acc[mt][1]*rcp, acc[mt][2]*rcp, acc[mt][3]*rcp };
    *reinterpret_cast<float4*>(wrow + mt * 16) = wv;
    hpair[mt*2+0] = pack2(acc[mt][0], acc[mt][1]);
    hpair[mt*2+1] = pack2(acc[mt][2], acc[mt][3]);
  }

  f32x4 oacc[16];
  #pragma unroll
  for (int dt = 0; dt < 16; ++dt) { f32x4 z = {}; oacc[dt] = z; }

  const int addrA = ((2*(g&1) + 0)*16 + c) * 4;
  const int addrB = ((2*(g&1) + 1)*16 + c) * 4;
  const bool hig = (g >= 2);

  // GEMM2 phase P: V-chunk P from buf P&3; B-frag via 8 bpermutes
#define G2C(P) { \
    const char* bufp = lds + ((P)&3)*16384; \
    u32x4 wf; \
    { \
      int v1 = __builtin_amdgcn_ds_bpermute(addrA, (int)hpair[4*(P)+0]); \
      int v2 = __builtin_amdgcn_ds_bpermute(addrA, (int)hpair[4*(P)+2]); \
      wf[0] = (u32)(hig ? v2 : v1); \
      v1 = __builtin_amdgcn_ds_bpermute(addrA, (int)hpair[4*(P)+1]); \
      v2 = __builtin_amdgcn_ds_bpermute(addrA, (int)hpair[4*(P)+3]); \
      wf[1] = (u32)(hig ? v2 : v1); \
      v1 = __builtin_amdgcn_ds_bpermute(addrB, (int)hpair[4*(P)+0]); \
      v2 = __builtin_amdgcn_ds_bpermute(addrB, (int)hpair[4*(P)+2]); \
      wf[2] = (u32)(hig ? v2 : v1); \
      v1 = __builtin_amdgcn_ds_bpermute(addrB, (int)hpair[4*(P)+1]); \
      v2 = __builtin_amdgcn_ds_bpermute(addrB, (int)hpair[4*(P)+3]); \
      wf[3] = (u32)(hig ? v2 : v1); \
    } \
    bf16x8 bfrag = __builtin_bit_cast(bf16x8, wf); \
    _Pragma("unroll") \
    for (int dt = 0; dt < 16; ++dt) { \
      bf16x8 af = *reinterpret_cast<const bf16x8*>(bufp + dt*1024 + lane*16); \
      oacc[dt] = __builtin_amdgcn_mfma_f32_16x16x32_bf16(af, bfrag, oacc[dt], 0, 0, 0); \
    } }

  // ---- GEMM2: 16 phases. Phases 0-2 use conservative vmcnt(8): V0..V2 are
  // older than {V-next stages + 32 W stores}, so vmcnt(8) provably retires
  // them regardless of how the scheduler interleaved the stores.
  PH(8, vptr+ 3*16384, 3)  G2C(0)
  PH(8, vptr+ 4*16384, 0)  G2C(1)
  PH(8, vptr+ 5*16384, 1)  G2C(2)
  PH(8, vptr+ 6*16384, 2)  G2C(3)
  PH(8, vptr+ 7*16384, 3)  G2C(4)
  PH(8, vptr+ 8*16384, 0)  G2C(5)
  PH(8, vptr+ 9*16384, 1)  G2C(6)
  PH(8, vptr+10*16384, 2)  G2C(7)
  PH(8, vptr+11*16384, 3)  G2C(8)
  PH(8, vptr+12*16384, 0)  G2C(9)
  PH(8, vptr+13*16384, 1)  G2C(10)
  PH(8, vptr+14*16384, 2)  G2C(11)
  PH(8, vptr+15*16384, 3)  G2C(12)
  PHX(8)                    G2C(13)
  PHX(4)                    G2C(14)
  PHX(0)                    G2C(15)

  // ---- O store (scaled by 1/sum)
  float* orow = out_o + (size_t)row * DIM + g * 4;
  #pragma unroll
  for (int dt = 0; dt < 16; ++dt) {
    float4 ov = { oacc[dt][0]*rcp, oacc[dt][1]*rcp, oacc[dt][2]*rcp, oacc[dt][3]*rcp };
    *reinterpret_cast<float4*>(orow + dt * 16) = ov;
  }
}

// Boundary scene diffs: i % 16 == 15 (one wave per i)
__global__ void scene_bound(const float* __restrict__ q, float* __restrict__ out_s, int B) {
  int widx = (blockIdx.x * blockDim.x + threadIdx.x) >> 6;
  int lane = threadIdx.x & 63;
  int i = widx * 16 + 15;
  if (i > B - 2) return;
  const float* a = q + (size_t)i * DIM + lane * 4;
  float4 x = *reinterpret_cast<const float4*>(a);
  float4 y = *reinterpret_cast<const float4*>(a + DIM);
  float dx = y.x-x.x, dy = y.y-x.y, dz = y.z-x.z, dw = y.w-x.w;
  float sd = dx*dx + dy*dy + dz*dz + dw*dw;
  #pragma unroll
  for (int o = 1; o < 64; o <<= 1) sd += __shfl_xor(sd, o);
  if (lane == 0) out_s[i] = (sqrtf(sd) < 0.8f) ? 1.0f : 0.0f;
}

extern "C" void kernel_launch(void* const* d_in, const int* in_sizes, int n_in,
                              void* d_out, int out_size, void* d_ws, size_t ws_size,
                              hipStream_t stream) {
  const float* q  = (const float*)d_in[0];
  const float* mk = (const float*)d_in[1];
  const float* mv = (const float*)d_in[2];
  int B = in_sizes[0] / DIM;            // 131072
  float* o = (float*)d_out;
  float* w = o + (size_t)B * DIM;
  float* s = w + (size_t)B * MEMN;
  u16* knf = (u16*)d_ws;                         // 256 KB
  u16* vtf = (u16*)((char*)d_ws + 262144);       // 256 KB
  prep_keys<<<128, 256, 0, stream>>>(mk, knf);
  prep_vals<<<128, 256, 0, stream>>>(mv, vtf);
  fused_main<<<B / 64, 256, 0, stream>>>(q, knf, vtf, o, w, s);
  int nwaves = B / 16;
  scene_bound<<<(nwaves + 3) / 4, 256, 0, stream>>>(q, s, B);
}

// Round 5
// 176.262 us; speedup vs baseline: 1.0900x; 1.0900x over previous
//
#include <hip/hip_runtime.h>
#include <hip/hip_bf16.h>

#define DIM 256
#define MEMN 512
#define TEMPF 10.0f

typedef float f32x4 __attribute__((ext_vector_type(4)));
typedef __bf16 bf16x8 __attribute__((ext_vector_type(8)));
typedef unsigned int u32;
typedef unsigned short u16;
typedef u32 u32x4 __attribute__((ext_vector_type(4)));

typedef __attribute__((address_space(1))) unsigned int as1_u32;
typedef __attribute__((address_space(3))) unsigned int as3_u32;

__device__ __forceinline__ void gll16(const void* gp, void* lp) {
  __builtin_amdgcn_global_load_lds((const as1_u32*)gp, (as3_u32*)lp, 16, 0, 0);
}

__device__ __forceinline__ u16 bf16bits(float x) {
  __bf16 h = (__bf16)x;
  return __builtin_bit_cast(u16, h);
}
__device__ __forceinline__ u32 pack2(float a, float b) {
  return (u32)bf16bits(a) | ((u32)bf16bits(b) << 16);
}

// KnFrag[kc][mt][lane][j] = Kn_norm[mt*16+(lane&15)][kc*32+(lane>>4)*8+j], kc<8, mt<32
__global__ void prep_keys(const float* __restrict__ keys, u16* __restrict__ knf) {
  int lane = threadIdx.x & 63;
  int m = blockIdx.x * 4 + (threadIdx.x >> 6);
  float4 v = *reinterpret_cast<const float4*>(keys + (size_t)m * DIM + lane * 4);
  float ss = v.x*v.x + v.y*v.y + v.z*v.z + v.w*v.w;
  #pragma unroll
  for (int o = 1; o < 64; o <<= 1) ss += __shfl_xor(ss, o);
  float rn = 1.0f / fmaxf(sqrtf(ss), 1e-12f);
  float vals[4] = {v.x*rn, v.y*rn, v.z*rn, v.w*rn};
  int mt = m >> 4, ml = m & 15;
  #pragma unroll
  for (int t = 0; t < 4; ++t) {
    int d = lane * 4 + t;
    int kc = d >> 5, gg = (d >> 3) & 3, j = d & 7;
    knf[(size_t)((kc*32 + mt)*64 + gg*16 + ml)*8 + j] = bf16bits(vals[t]);
  }
}

// VtFrag[kc][dt][lane][j] = V[kc*32+(lane>>4)*8+j][dt*16+(lane&15)], kc<16, dt<16
__global__ void prep_vals(const float* __restrict__ mv, u16* __restrict__ vtf) {
  int lane = threadIdx.x & 63;
  int m = blockIdx.x * 4 + (threadIdx.x >> 6);
  float4 v = *reinterpret_cast<const float4*>(mv + (size_t)m * DIM + lane * 4);
  float vals[4] = {v.x, v.y, v.z, v.w};
  int kc = m >> 5, gg = (m >> 3) & 3, j = m & 7;
  #pragma unroll
  for (int t = 0; t < 4; ++t) {
    int d = lane * 4 + t;
    int dt = d >> 4, dl = d & 15;
    vtf[(size_t)((kc*16 + dt)*64 + gg*16 + dl)*8 + j] = bf16bits(vals[t]);
  }
}

// counted vmcnt + lgkmcnt(0) drain (WAR fix, round-4-verified) before barrier
#define WAITCNTS(N) asm volatile("s_waitcnt vmcnt(" #N ") lgkmcnt(0)" ::: "memory")
#define CLB    asm volatile("" ::: "memory")
#define SCHEDB __builtin_amdgcn_sched_barrier(0)

// 256 threads (4 waves), 64 rows/block. 16KB phases, 4-buf LDS rotation,
// depth-3 prefetch, Q-loads spread through GEMM1, W-stores spread through
// GEMM2. All vmem in CLOBBER-pinned regions; vmcnt N = minimum count of ops
// newer than the needed stage (derived from the pinned stream, in comments).
__global__ __launch_bounds__(256, 2) void fused_main(
    const float* __restrict__ q, const u16* __restrict__ knf,
    const u16* __restrict__ vtf, float* __restrict__ out_o,
    float* __restrict__ out_w, float* __restrict__ out_s) {
  __shared__ __align__(16) char lds[65536];   // 4 x 16KB rotating buffers
  const int tid = threadIdx.x;
  const int wave = tid >> 6, lane = tid & 63;
  const int g = lane >> 4, c = lane & 15;
  const int row = blockIdx.x * 64 + wave * 16 + c;

  const char* kptr = (const char*)knf;
  const char* vptr = (const char*)vtf;

  auto stage16 = [&](const char* src, char* dst) {
    #pragma unroll
    for (int i = 0; i < 4; ++i)
      gll16(src + i*4096 + tid*16, dst + i*4096 + wave*1024);
  };

  const float* qrow = q + (size_t)row * DIM + g * 8;
  float qraw[2][8];                 // ping-pong chunk buffers (static idx only)
  bf16x8 qbf[8];
  float sd = 0.f, ss = 0.f;

  // load Q chunk J (2 dwordx4) into slot J&1
#define QLOAD(J) { \
    float4 a = *reinterpret_cast<const float4*>(qrow + (J)*32); \
    float4 b = *reinterpret_cast<const float4*>(qrow + (J)*32 + 4); \
    qraw[(J)&1][0]=a.x; qraw[(J)&1][1]=a.y; qraw[(J)&1][2]=a.z; qraw[(J)&1][3]=a.w; \
    qraw[(J)&1][4]=b.x; qraw[(J)&1][5]=b.y; qraw[(J)&1][6]=b.z; qraw[(J)&1][7]=b.w; }

  // convert chunk J: scene-diff + sum-sq accumulate + bf16 (deferred norm)
#define QCONV(J) { \
    _Pragma("unroll") \
    for (int e = 0; e < 8; ++e) { \
      float x = qraw[(J)&1][e]; \
      float nb = __shfl_down(x, 1); \
      float d0 = nb - x; \
      sd += d0 * d0; \
      ss += x * x; \
      qbf[(J)][e] = (__bf16)x; \
    } }

  // ---- prologue: Q chunks 0,1 (4 loads), then K0..K2 (12 stage ops), pinned
  QLOAD(0) QLOAD(1) CLB;
  stage16(kptr + 0*16384, lds + 0*16384); CLB;
  stage16(kptr + 1*16384, lds + 1*16384); CLB;
  stage16(kptr + 2*16384, lds + 2*16384); CLB;
  QCONV(0) QCONV(1)

  f32x4 acc[32];
  #pragma unroll
  for (int mt = 0; mt < 32; ++mt) { f32x4 z = {}; acc[mt] = z; }

#define G1C(P) { \
    const char* bufp = lds + ((P)&3)*16384; \
    _Pragma("unroll") \
    for (int mt = 0; mt < 16; ++mt) { \
      bf16x8 af = *reinterpret_cast<const bf16x8*>(bufp + mt*1024 + lane*16); \
      acc[((P)&1)*16+mt] = __builtin_amdgcn_mfma_f32_16x16x32_bf16(af, qbf[(P)>>1], acc[((P)&1)*16+mt], 0, 0, 0); \
    } }

#define PH(NV, SRC, DB) WAITCNTS(NV); __builtin_amdgcn_s_barrier(); SCHEDB; \
    stage16((SRC), lds + (DB)*16384); CLB;
#define PHX(NV) WAITCNTS(NV); __builtin_amdgcn_s_barrier(); SCHEDB;

  // ---- GEMM1: pinned vmem stream per phase: stage(4) [+ qload(2)]
  // need S_p retired at phase-p barrier; N = min ops newer than S_p.
  PH(8,  kptr+ 3*16384, 3) QLOAD(2) CLB; G1C(0)
  PH(10, kptr+ 4*16384, 0) G1C(1)
  PH(10, kptr+ 5*16384, 1) QLOAD(3) CLB; QCONV(2) G1C(2)
  PH(12, kptr+ 6*16384, 2) G1C(3)
  PH(10, kptr+ 7*16384, 3) QLOAD(4) CLB; QCONV(3) G1C(4)
  PH(12, kptr+ 8*16384, 0) G1C(5)
  PH(10, kptr+ 9*16384, 1) QLOAD(5) CLB; QCONV(4) G1C(6)
  PH(12, kptr+10*16384, 2) G1C(7)
  PH(10, kptr+11*16384, 3) QLOAD(6) CLB; QCONV(5) G1C(8)
  PH(12, kptr+12*16384, 0) G1C(9)
  PH(10, kptr+13*16384, 1) QLOAD(7) CLB; QCONV(6) G1C(10)
  PH(12, kptr+14*16384, 2) G1C(11)
  PH(10, kptr+15*16384, 3) QCONV(7) G1C(12)
  PH(10, vptr+ 0*16384, 0) G1C(13)
  PH(8,  vptr+ 1*16384, 1) G1C(14)
  PH(8,  vptr+ 2*16384, 2) G1C(15)

  // ---- reductions + softmax (V0..V2 staging in flight; pure VALU here)
  sd += __shfl_xor(sd, 16); sd += __shfl_xor(sd, 32);
  ss += __shfl_xor(ss, 16); ss += __shfl_xor(ss, 32);
  if (g == 0 && c < 15)
    out_s[row] = (sqrtf(sd) < 0.8f) ? 1.0f : 0.0f;
  float rn = 1.0f / fmaxf(sqrtf(ss), 1e-12f);
  float scale = TEMPF * rn;          // deferred L2-norm folded into exponent
  float sum = 0.f;
  #pragma unroll
  for (int mt = 0; mt < 32; ++mt) {
    #pragma unroll
    for (int i = 0; i < 4; ++i) {
      float e = __expf(acc[mt][i] * scale);
      acc[mt][i] = e;
      sum += e;
    }
  }
  sum += __shfl_xor(sum, 16); sum += __shfl_xor(sum, 32);
  float rcp = 1.0f / sum;

  f32x4 oacc[16];
  #pragma unroll
  for (int dt = 0; dt < 16; ++dt) { f32x4 z = {}; oacc[dt] = z; }

  const int addrA = ((2*(g&1) + 0)*16 + c) * 4;
  const int addrB = ((2*(g&1) + 1)*16 + c) * 4;
  const bool hig = (g >= 2);
  float* wrow = out_w + (size_t)row * MEMN + g * 4;

  // W chunk P: rows' m-tiles 2P,2P+1 scaled by rcp (2 float4 stores)
#define WST(P) { \
    float4 w0 = { acc[2*(P)][0]*rcp, acc[2*(P)][1]*rcp, acc[2*(P)][2]*rcp, acc[2*(P)][3]*rcp }; \
    *reinterpret_cast<float4*>(wrow + (2*(P))*16) = w0; \
    float4 w1 = { acc[2*(P)+1][0]*rcp, acc[2*(P)+1][1]*rcp, acc[2*(P)+1][2]*rcp, acc[2*(P)+1][3]*rcp }; \
    *reinterpret_cast<float4*>(wrow + (2*(P)+1)*16) = w1; }

  // GEMM2 phase P: pack e->bf16 pairs from acc (no hpair array), bpermute,
  // 16 MFMAs on V chunk P (buf P&3)
#define G2C(P) { \
    const char* bufp = lds + ((P)&3)*16384; \
    u32 p0 = pack2(acc[2*(P)][0],   acc[2*(P)][1]); \
    u32 p1 = pack2(acc[2*(P)][2],   acc[2*(P)][3]); \
    u32 p2 = pack2(acc[2*(P)+1][0], acc[2*(P)+1][1]); \
    u32 p3 = pack2(acc[2*(P)+1][2], acc[2*(P)+1][3]); \
    u32x4 wf; \
    { \
      int v1 = __builtin_amdgcn_ds_bpermute(addrA, (int)p0); \
      int v2 = __builtin_amdgcn_ds_bpermute(addrA, (int)p2); \
      wf[0] = (u32)(hig ? v2 : v1); \
      v1 = __builtin_amdgcn_ds_bpermute(addrA, (int)p1); \
      v2 = __builtin_amdgcn_ds_bpermute(addrA, (int)p3); \
      wf[1] = (u32)(hig ? v2 : v1); \
      v1 = __builtin_amdgcn_ds_bpermute(addrB, (int)p0); \
      v2 = __builtin_amdgcn_ds_bpermute(addrB, (int)p2); \
      wf[2] = (u32)(hig ? v2 : v1); \
      v1 = __builtin_amdgcn_ds_bpermute(addrB, (int)p1); \
      v2 = __builtin_amdgcn_ds_bpermute(addrB, (int)p3); \
      wf[3] = (u32)(hig ? v2 : v1); \
    } \
    bf16x8 bfrag = __builtin_bit_cast(bf16x8, wf); \
    _Pragma("unroll") \
    for (int dt = 0; dt < 16; ++dt) { \
      bf16x8 af = *reinterpret_cast<const bf16x8*>(bufp + dt*1024 + lane*16); \
      oacc[dt] = __builtin_amdgcn_mfma_f32_16x16x32_bf16(af, bfrag, oacc[dt], 0, 0, 0); \
    } }

  // ---- GEMM2: pinned stream per phase: stage(4) + Wstore(2); P>=13 W only.
  // N derivation (need SV_P at phase-P barrier):
  // P=0: SV1,SV2 newer = 8.  P=1: SV2 + (SV3+W) = 10.  P=2: 6+6 = 12.
  // P=3..13: W(2) after SV in its phase + 6 + 6 = 14.
  // P=14: 2 + 6 + W(2) = 10.  P=15: 2+2+2 = 6.
  PH(8,  vptr+ 3*16384, 3) WST(0)  CLB; G2C(0)
  PH(10, vptr+ 4*16384, 0) WST(1)  CLB; G2C(1)
  PH(12, vptr+ 5*16384, 1) WST(2)  CLB; G2C(2)
  PH(14, vptr+ 6*16384, 2) WST(3)  CLB; G2C(3)
  PH(14, vptr+ 7*16384, 3) WST(4)  CLB; G2C(4)
  PH(14, vptr+ 8*16384, 0) WST(5)  CLB; G2C(5)
  PH(14, vptr+ 9*16384, 1) WST(6)  CLB; G2C(6)
  PH(14, vptr+10*16384, 2) WST(7)  CLB; G2C(7)
  PH(14, vptr+11*16384, 3) WST(8)  CLB; G2C(8)
  PH(14, vptr+12*16384, 0) WST(9)  CLB; G2C(9)
  PH(14, vptr+13*16384, 1) WST(10) CLB; G2C(10)
  PH(14, vptr+14*16384, 2) WST(11) CLB; G2C(11)
  PH(14, vptr+15*16384, 3) WST(12) CLB; G2C(12)
  PHX(14)                  WST(13) CLB; G2C(13)
  PHX(10)                  WST(14) CLB; G2C(14)
  PHX(6)                   WST(15) CLB; G2C(15)

  // ---- O store (scaled by 1/sum)
  float* orow = out_o + (size_t)row * DIM + g * 4;
  #pragma unroll
  for (int dt = 0; dt < 16; ++dt) {
    float4 ov = { oacc[dt][0]*rcp, oacc[dt][1]*rcp, oacc[dt][2]*rcp, oacc[dt][3]*rcp };
    *reinterpret_cast<float4*>(orow + dt * 16) = ov;
  }
}

// Boundary scene diffs: i % 16 == 15 (one wave per i)
__global__ void scene_bound(const float* __restrict__ q, float* __restrict__ out_s, int B) {
  int widx = (blockIdx.x * blockDim.x + threadIdx.x) >> 6;
  int lane = threadIdx.x & 63;
  int i = widx * 16 + 15;
  if (i > B - 2) return;
  const float* a = q + (size_t)i * DIM + lane * 4;
  float4 x = *reinterpret_cast<const float4*>(a);
  float4 y = *reinterpret_cast<const float4*>(a + DIM);
  float dx = y.x-x.x, dy = y.y-x.y, dz = y.z-x.z, dw = y.w-x.w;
  float sd = dx*dx + dy*dy + dz*dz + dw*dw;
  #pragma unroll
  for (int o = 1; o < 64; o <<= 1) sd += __shfl_xor(sd, o);
  if (lane == 0) out_s[i] = (sqrtf(sd) < 0.8f) ? 1.0f : 0.0f;
}

extern "C" void kernel_launch(void* const* d_in, const int* in_sizes, int n_in,
                              void* d_out, int out_size, void* d_ws, size_t ws_size,
                              hipStream_t stream) {
  const float* q  = (const float*)d_in[0];
  const float* mk = (const float*)d_in[1];
  const float* mv = (const float*)d_in[2];
  int B = in_sizes[0] / DIM;            // 131072
  float* o = (float*)d_out;
  float* w = o + (size_t)B * DIM;
  float* s = w + (size_t)B * MEMN;
  u16* knf = (u16*)d_ws;                         // 256 KB
  u16* vtf = (u16*)((char*)d_ws + 262144);       // 256 KB
  prep_keys<<<128, 256, 0, stream>>>(mk, knf);
  prep_vals<<<128, 256, 0, stream>>>(mv, vtf);
  fused_main<<<B / 64, 256, 0, stream>>>(q, knf, vtf, o, w, s);
  int nwaves = B / 16;
  scene_bound<<<(nwaves + 3) / 4, 256, 0, stream>>>(q, s, B);
}